// Round 8
// baseline (312.627 us; speedup 1.0000x reference)
//
#include <hip/hip_runtime.h>
#include <hip/hip_bf16.h>

// ---------------- problem constants ----------------
#define T_SEQ 8192
#define DMODEL 1024
#define DINNER 2048          // DI
#define NSTATE 16            // DS
#define NCH 128              // scan chunks
#define CL 64                // chunk length (NCH*CL = T_SEQ)

typedef __attribute__((ext_vector_type(8))) short bf16x8;   // 8 bf16 = 4 VGPRs
typedef __attribute__((ext_vector_type(4))) float f32x4;    // MFMA C/D frag

__device__ __forceinline__ float bf2f(ushort u) {
  union { unsigned u; float f; } c; c.u = ((unsigned)u) << 16; return c.f;
}
__device__ __forceinline__ ushort f2bf(float f) {
  union { float f; unsigned u; } c; c.f = f;
  unsigned r = c.u + 0x7FFFu + ((c.u >> 16) & 1u);   // RNE
  return (ushort)(r >> 16);
}

#define GLD16(dst, src) __builtin_amdgcn_global_load_lds( \
    (const __attribute__((address_space(1))) void*)(src), \
    (__attribute__((address_space(3))) void*)(dst), 16, 0, 0)

template<int N> __device__ __forceinline__ void waitcnt_vm() {
  asm volatile("s_waitcnt vmcnt(%0)" :: "i"(N) : "memory");
}
#define LGKM0() do { asm volatile("s_waitcnt lgkmcnt(0)" ::: "memory"); \
                     __builtin_amdgcn_sched_barrier(0); } while (0)
#define BAR() do { __builtin_amdgcn_sched_barrier(0); __builtin_amdgcn_s_barrier(); \
                   __builtin_amdgcn_sched_barrier(0); } while (0)

// ---------------- prep kernels ----------------
__global__ __launch_bounds__(256) void cast_bf16(const float* __restrict__ in,
                                                 ushort* __restrict__ out, int n4) {
  int i = blockIdx.x * 256 + threadIdx.x;
  if (i < n4) {
    float4 v = ((const float4*)in)[i];
    ushort4 o;
    o.x = f2bf(v.x); o.y = f2bf(v.y); o.z = f2bf(v.z); o.w = f2bf(v.w);
    ((ushort4*)out)[i] = o;
  }
}

// in[R][C] f32 -> out[C][R] bf16   (grid: (C/32, R/32), block (32,8))
__global__ __launch_bounds__(256) void transpose_bf16(const float* __restrict__ in,
                                                      ushort* __restrict__ out, int R, int C) {
  __shared__ float tile[32][33];
  int bx = blockIdx.x * 32;   // C base
  int by = blockIdx.y * 32;   // R base
  int x = threadIdx.x, y = threadIdx.y;
#pragma unroll
  for (int j = 0; j < 32; j += 8)
    tile[y + j][x] = in[(size_t)(by + y + j) * C + bx + x];
  __syncthreads();
#pragma unroll
  for (int j = 0; j < 32; j += 8)
    out[(size_t)(bx + y + j) * R + by + x] = f2bf(tile[x][y + j]);
}

// W_x[2048][33] f32 -> wx48[48][2048] bf16 (transposed, zero-padded rows 33..47)
__global__ __launch_bounds__(256) void wx_transpose_pad(const float* __restrict__ Wx,
                                                        ushort* __restrict__ wxT) {
  int idx = blockIdx.x * 256 + threadIdx.x;   // 48*2048
  int j = idx >> 11;
  int k = idx & 2047;
  wxT[idx] = (j < 33) ? f2bf(Wx[k * 33 + j]) : (ushort)0;
}

// ---- GEMM: BM=BN=128, BK=32, 4 waves (2Mx2N), 4-deep ring, 2 blocks/CU ----
// C[M][N] = A[M][K] * B^T, bf16 row-major K-contig. M/128 must be 64 (8 mtiles/XCD).
// Per K-tile: 1 STAGE (4 GLD16, tile t+3) issued FIRST, 8 ds_read_b128, lgkm0,
// 16 MFMA in setprio, 1 counted vmcnt(8), 1 barrier. 2 blocks/CU provide the
// latency overlap (R6 evidence: block-level async ~= phase interleave).
// LDS layout: tile [128 rows][32 k] as 64 lines of 128B; line = row-pair
// (2r:k0-31, 2r+1:k0-31 as 8 x 16B slots); slot ^= (line&7) (conflict-free
// profile identical to R7's measured-0 layout). Pre-swizzled global source
// (linear GLD16 dest, rule #21), same XOR on ds_read.
// vmcnt(8) forces t+1 landed (issued at top of t-2, ~3 tiles slack >> HBM 900cy),
// keeps t+2/t+3 (8 loads) in flight. Tail: vmcnt(4)/vmcnt(0).
// L2-compact map: xcd owns 8 mtiles; concurrent 64-block group = 8m x 8n
// -> working set A 2MB + B 2MB = 4MB = one XCD L2.
// OUTMODE: 0 = f32 out; 1 = bf16 split xc/z (block-uniform by nbase).
template<int OUTMODE>
__global__ __launch_bounds__(256, 2)
void gemm_r8(const ushort* __restrict__ A, const ushort* __restrict__ B,
             void* __restrict__ out0, void* __restrict__ out1,
             int N, int K) {
  extern __shared__ __align__(16) char smem[];   // A ring 32KB + B ring 32KB
  char* const sB = smem + 32768;

  const int tid = threadIdx.x, lane = tid & 63, wid = tid >> 6;
  const int wm = wid >> 1, wn = wid & 1;
  const int xcd = blockIdx.x & 7, jb = blockIdx.x >> 3;
  const int mtile = xcd * 8 + ((jb >> 3) & 7);
  const int ntile = (jb >> 6) * 8 + (jb & 7);
  const int mbase = mtile * 128, nbase = ntile * 128;
  const int NT = K >> 5;

  // staging source (pre-swizzled): granule g=j*256+tid -> line=g>>3, slot=g&7
  // src slot s'=slot^(line&7); row=2*line+(s'>>2); col=(s'&3)*8
  const ushort* pa[2];
  const ushort* pb[2];
#pragma unroll
  for (int j = 0; j < 2; ++j) {
    int g = j * 256 + tid;
    int line = g >> 3, sl = (g & 7) ^ (line & 7);
    int row = 2 * line + (sl >> 2), col = (sl & 3) << 3;
    pa[j] = A + (size_t)(mbase + row) * K + col;
    pb[j] = B + (size_t)(nbase + row) * K + col;
  }

#define STAGE(slot, tt) do { \
    char* _da = smem + (slot) * 8192 + wid * 1024; \
    char* _db = sB   + (slot) * 8192 + wid * 1024; \
    GLD16(_da,        pa[0] + (size_t)(tt) * 32); \
    GLD16(_da + 4096, pa[1] + (size_t)(tt) * 32); \
    GLD16(_db,        pb[0] + (size_t)(tt) * 32); \
    GLD16(_db + 4096, pb[1] + (size_t)(tt) * 32); } while (0)

  // ds_read offsets: row r, k-half hh -> line=r>>1, slot=(((r&1)<<2)|hh)^(line&7)
  const int frow = lane & 15, hh = lane >> 4;
  int aoff[4], boff[4];
#pragma unroll
  for (int m = 0; m < 4; ++m) {
    int r = wm * 64 + m * 16 + frow;
    aoff[m] = (r >> 1) * 128 + (((((r & 1) << 2) | hh)) ^ ((r >> 1) & 7)) * 16;
    int rb = wn * 64 + m * 16 + frow;
    boff[m] = (rb >> 1) * 128 + (((((rb & 1) << 2) | hh)) ^ ((rb >> 1) & 7)) * 16;
  }

  f32x4 acc[4][4];
#pragma unroll
  for (int m = 0; m < 4; ++m)
#pragma unroll
    for (int n = 0; n < 4; ++n) acc[m][n] = (f32x4){0.f, 0.f, 0.f, 0.f};

  // prologue: tiles 0,1,2 staged; force tile 0 landed (8 left in flight)
  STAGE(0, 0); STAGE(1, 1); STAGE(2, 2);
  waitcnt_vm<8>();
  BAR();

  for (int t = 0; t < NT; ++t) {
    const int slot = t & 3;
    if (t + 3 < NT) STAGE((t + 3) & 3, t + 3);   // writes slot (t-1)&3: safe
    const char* bA = smem + slot * 8192;
    const char* bB = sB + slot * 8192;
    bf16x8 a[4], b[4];
#pragma unroll
    for (int m = 0; m < 4; ++m) a[m] = *(const bf16x8*)(bA + aoff[m]);
#pragma unroll
    for (int n = 0; n < 4; ++n) b[n] = *(const bf16x8*)(bB + boff[n]);
    LGKM0();
    __builtin_amdgcn_s_setprio(1);
#pragma unroll
    for (int m = 0; m < 4; ++m)
#pragma unroll
      for (int n = 0; n < 4; ++n)
        acc[m][n] = __builtin_amdgcn_mfma_f32_16x16x32_bf16(a[m], b[n], acc[m][n], 0, 0, 0);
    __builtin_amdgcn_s_setprio(0);
    if (t + 3 < NT)      waitcnt_vm<8>();
    else if (t + 2 < NT) waitcnt_vm<4>();
    else if (t + 1 < NT) waitcnt_vm<0>();
    BAR();
  }

  // epilogue: C/D layout col=lane&15, row=(lane>>4)*4+reg  [m89/m91]
  const int crow0 = mbase + wm * 64 + (lane >> 4) * 4;
  const int ccol0 = wn * 64 + (lane & 15);
  if (OUTMODE == 0) {
    float* po = (float*)out0;
#pragma unroll
    for (int m = 0; m < 4; ++m)
#pragma unroll
      for (int n = 0; n < 4; ++n)
#pragma unroll
        for (int j = 0; j < 4; ++j)
          po[(size_t)(crow0 + m * 16 + j) * N + nbase + ccol0 + n * 16] = acc[m][n][j];
  } else {
    ushort* dst = (nbase < 2048) ? (ushort*)out0 : (ushort*)out1;
    const int cbase = (nbase & 2047) + ccol0;
#pragma unroll
    for (int m = 0; m < 4; ++m)
#pragma unroll
      for (int n = 0; n < 4; ++n)
#pragma unroll
        for (int j = 0; j < 4; ++j)
          dst[(size_t)(crow0 + m * 16 + j) * 2048 + cbase + n * 16] = f2bf(acc[m][n][j]);
  }
#undef STAGE
}

// ---------------- thin GEMM: xdbl = xs @ W_x (N=48 pad), 4-way split-K ----------------
__global__ __launch_bounds__(256) void gemm_thin(const ushort* __restrict__ A,
                                                 const ushort* __restrict__ Bw,
                                                 float* __restrict__ part) {
  __shared__ __align__(16) ushort sA[128 * 64];   // 16 KB
  __shared__ __align__(16) ushort sB[48 * 64];    // 6 KB
  const int tid = threadIdx.x, lane = tid & 63, wid = tid >> 6;
  const int mbase = blockIdx.x * 128;
  const int kbase = blockIdx.y * 512;
  const int frow = lane & 15, fke = (lane >> 4) * 8;

  f32x4 acc[2][3];
#pragma unroll
  for (int m = 0; m < 2; ++m)
#pragma unroll
    for (int n = 0; n < 3; ++n) acc[m][n] = (f32x4){0.f, 0.f, 0.f, 0.f};

  for (int k0 = 0; k0 < 512; k0 += 64) {
#pragma unroll
    for (int j = 0; j < 4; ++j) {
      int o = tid * 16 + j * 4096;
      int row = o >> 7, ke = ((o >> 4) & 7) * 8;
      GLD16((char*)sA + wid * 1024 + j * 4096,
            A + (size_t)(mbase + row) * DINNER + kbase + k0 + ke);
    }
    for (int i = tid; i < 384; i += 256) {
      int brow = i >> 3, kc = (i & 7) * 8;
      *(bf16x8*)&sB[brow * 64 + kc] = *(const bf16x8*)(Bw + (size_t)brow * DINNER + kbase + k0 + kc);
    }
    __syncthreads();
    bf16x8 af[2][2], bf_[3][2];
#pragma unroll
    for (int m = 0; m < 2; ++m)
#pragma unroll
      for (int ks = 0; ks < 2; ++ks)
        af[m][ks] = *(const bf16x8*)&sA[(wid * 32 + m * 16 + frow) * 64 + ks * 32 + fke];
#pragma unroll
    for (int n = 0; n < 3; ++n)
#pragma unroll
      for (int ks = 0; ks < 2; ++ks)
        bf_[n][ks] = *(const bf16x8*)&sB[(n * 16 + frow) * 64 + ks * 32 + fke];
#pragma unroll
    for (int m = 0; m < 2; ++m)
#pragma unroll
      for (int n = 0; n < 3; ++n)
#pragma unroll
        for (int ks = 0; ks < 2; ++ks)
          acc[m][n] = __builtin_amdgcn_mfma_f32_16x16x32_bf16(af[m][ks], bf_[n][ks], acc[m][n], 0, 0, 0);
    __syncthreads();
  }
  float* po = part + (size_t)blockIdx.y * (T_SEQ * 48);
#pragma unroll
  for (int m = 0; m < 2; ++m)
#pragma unroll
    for (int n = 0; n < 3; ++n)
#pragma unroll
      for (int j = 0; j < 4; ++j) {
        int rr = mbase + wid * 32 + m * 16 + (lane >> 4) * 4 + j;
        int cc = n * 16 + (lane & 15);
        po[(size_t)rr * 48 + cc] = acc[m][n][j];
      }
}

__global__ __launch_bounds__(256) void reduce4(const float* __restrict__ part,
                                               float* __restrict__ xdbl) {
  int i = blockIdx.x * 256 + threadIdx.x;
  const float4* p = (const float4*)part;
  float4 a = p[i], b = p[i + 98304], c = p[i + 2 * 98304], d = p[i + 3 * 98304];
  ((float4*)xdbl)[i] = make_float4(a.x + b.x + c.x + d.x, a.y + b.y + c.y + d.y,
                                   a.z + b.z + c.z + d.z, a.w + b.w + c.w + d.w);
}

// -------- depthwise causal conv (DC=4) + silu, scalar (coalesced weights) --------
__global__ __launch_bounds__(256) void conv_silu(const ushort* __restrict__ xc,
                                                 const float* __restrict__ cw,
                                                 const float* __restrict__ cb,
                                                 ushort* __restrict__ xs) {
  int idx = blockIdx.x * 256 + threadIdx.x;   // t*2048 + d
  int t = idx >> 11, d = idx & 2047;
  float4 w = *(const float4*)(cw + d * 4);    // 16B lane-stride: coalesced
  float a = cb[d];
  const float wk[4] = {w.x, w.y, w.z, w.w};
#pragma unroll
  for (int k = 0; k < 4; ++k) {
    int tt = t - 3 + k;
    if (tt >= 0) a += bf2f(xc[(size_t)tt * 2048 + d]) * wk[k];
  }
  float s = a / (1.f + expf(-a));
  xs[idx] = f2bf(s);
}

// ---------------- scan precompute (xdbl stride 48) ----------------
__global__ __launch_bounds__(256) void precompute_k(const float* __restrict__ xdbl,
                                                    const float* __restrict__ A_log,
                                                    float* __restrict__ abar,
                                                    float* __restrict__ bbar,
                                                    float* __restrict__ cc,
                                                    float* __restrict__ dlt) {
  int t = blockIdx.x * 256 + threadIdx.x;
  if (t >= T_SEQ) return;
  const float* r = xdbl + (size_t)t * 48;
  float v = r[0];
  float delta = (v > 20.f) ? v : log1pf(expf(v));
  dlt[t] = delta;
#pragma unroll
  for (int n = 0; n < NSTATE; ++n) {
    float A = -expf(A_log[n]);
    abar[t * 16 + n] = expf(delta * A);
    bbar[t * 16 + n] = delta * r[1 + n];
    cc[t * 16 + n]   = r[17 + n];
  }
}

__global__ __launch_bounds__(256) void chunkprod_k(const float* __restrict__ dlt,
                                                   const float* __restrict__ A_log,
                                                   float* __restrict__ P) {
  int idx = blockIdx.x * 256 + threadIdx.x;
  if (idx >= NCH * NSTATE) return;
  int c = idx >> 4, n = idx & 15;
  float s = 0.f;
  for (int i = 0; i < CL; ++i) s += dlt[c * CL + i];
  P[idx] = expf(-expf(A_log[n]) * s);
}

// ---------------- scan pass 1 (hend bf16) ----------------
__global__ __launch_bounds__(256) void scan1(const ushort* __restrict__ xs,
                                             const float* __restrict__ abar,
                                             const float* __restrict__ bbar,
                                             ushort* __restrict__ hend) {
  int c = blockIdx.x;
  int d = blockIdx.y * 256 + threadIdx.x;
  __shared__ float s_ab[CL * 16], s_bb[CL * 16];
  for (int e = threadIdx.x; e < CL * 16; e += 256) {
    s_ab[e] = abar[(size_t)c * CL * 16 + e];
    s_bb[e] = bbar[(size_t)c * CL * 16 + e];
  }
  __syncthreads();
  float h[16];
#pragma unroll
  for (int n = 0; n < 16; ++n) h[n] = 0.f;
  int tbase = c * CL;
  for (int i = 0; i < CL; ++i) {
    float x = bf2f(xs[(size_t)(tbase + i) * DINNER + d]);
#pragma unroll
    for (int n = 0; n < 16; ++n) h[n] = s_ab[i * 16 + n] * h[n] + s_bb[i * 16 + n] * x;
  }
  ushort* o = hend + ((size_t)c * DINNER + d) * 16;
  bf16x8 o0, o1;
#pragma unroll
  for (int q = 0; q < 8; ++q) { o0[q] = (short)f2bf(h[q]); o1[q] = (short)f2bf(h[8 + q]); }
  *(bf16x8*)o = o0;
  *(bf16x8*)(o + 8) = o1;
}

// ---------------- scan pass 2 (bf16 in/out, f32 carry) ----------------
__global__ __launch_bounds__(256) void scan2(const ushort* __restrict__ hend,
                                             const float* __restrict__ P,
                                             ushort* __restrict__ hin) {
  int idx = blockIdx.x * 256 + threadIdx.x;   // d*16 + n
  int n = idx & 15;
  float h = 0.f;
  for (int c = 0; c < NCH; ++c) {
    hin[(size_t)c * (DINNER * 16) + idx] = f2bf(h);
    h = P[c * 16 + n] * h + bf2f(hend[(size_t)c * (DINNER * 16) + idx]);
  }
}

// ---------------- scan pass 3 (hin bf16) ----------------
__global__ __launch_bounds__(256) void scan3(const ushort* __restrict__ xs,
                                             const ushort* __restrict__ zb,
                                             const float* __restrict__ abar,
                                             const float* __restrict__ bbar,
                                             const float* __restrict__ cc,
                                             const ushort* __restrict__ hin,
                                             const float* __restrict__ Dv,
                                             ushort* __restrict__ y) {
  int c = blockIdx.x;
  int d = blockIdx.y * 256 + threadIdx.x;
  __shared__ float s_ab[CL * 16], s_bb[CL * 16], s_cc[CL * 16];
  for (int e = threadIdx.x; e < CL * 16; e += 256) {
    s_ab[e] = abar[(size_t)c * CL * 16 + e];
    s_bb[e] = bbar[(size_t)c * CL * 16 + e];
    s_cc[e] = cc[(size_t)c * CL * 16 + e];
  }
  __syncthreads();
  float h[16];
  const ushort* hi = hin + ((size_t)c * DINNER + d) * 16;
  bf16x8 h0 = *(const bf16x8*)hi, h1 = *(const bf16x8*)(hi + 8);
#pragma unroll
  for (int q = 0; q < 8; ++q) { h[q] = bf2f((ushort)h0[q]); h[8 + q] = bf2f((ushort)h1[q]); }
  float Dd = Dv[d];
  int tbase = c * CL;
  for (int i = 0; i < CL; ++i) {
    size_t t = tbase + i;
    float x = bf2f(xs[t * DINNER + d]);
    float ys = 0.f;
#pragma unroll
    for (int n = 0; n < 16; ++n) {
      h[n] = s_ab[i * 16 + n] * h[n] + s_bb[i * 16 + n] * x;
      ys += s_cc[i * 16 + n] * h[n];
    }
    float z = bf2f(zb[t * 2048 + d]);
    float yv = (ys + Dd * x) * (z / (1.f + expf(-z)));
    y[t * DINNER + d] = f2bf(yv);
  }
}

// ---------------- launch ----------------
extern "C" void kernel_launch(void* const* d_in, const int* in_sizes, int n_in,
                              void* d_out, int out_size, void* d_ws, size_t ws_size,
                              hipStream_t stream) {
  const float* x      = (const float*)d_in[0];
  const float* W_in   = (const float*)d_in[1];
  const float* conv_w = (const float*)d_in[2];
  const float* conv_b = (const float*)d_in[3];
  const float* W_x    = (const float*)d_in[4];
  const float* A_log  = (const float*)d_in[5];
  const float* Dv     = (const float*)d_in[6];
  const float* W_out  = (const float*)d_in[7];
  float* out = (float*)d_out;

  char* w = (char*)d_ws;
  auto alloc = [&](size_t bytes) { char* p = w; w += (bytes + 255) & ~(size_t)255; return p; };

  ushort* xbf   = (ushort*)alloc((size_t)T_SEQ * DMODEL * 2);
  ushort* winT  = (ushort*)alloc((size_t)4096 * 1024 * 2);
  ushort* woutT = (ushort*)alloc((size_t)1024 * 2048 * 2);
  ushort* wxT   = (ushort*)alloc((size_t)48 * 2048 * 2);
  ushort* xc    = (ushort*)alloc((size_t)T_SEQ * DINNER * 2);
  ushort* zb    = (ushort*)alloc((size_t)T_SEQ * DINNER * 2);
  ushort* xs    = (ushort*)alloc((size_t)T_SEQ * DINNER * 2);
  float*  xdbl  = (float*) alloc((size_t)T_SEQ * 48 * 4);
  float*  parts = (float*) alloc((size_t)4 * T_SEQ * 48 * 4);
  float*  abar  = (float*) alloc((size_t)T_SEQ * 16 * 4);
  float*  bbar  = (float*) alloc((size_t)T_SEQ * 16 * 4);
  float*  ccb   = (float*) alloc((size_t)T_SEQ * 16 * 4);
  float*  dlt   = (float*) alloc((size_t)T_SEQ * 4);
  float*  P     = (float*) alloc((size_t)NCH * 16 * 4);
  ushort* hend  = (ushort*)alloc((size_t)NCH * DINNER * 16 * 2);
  ushort* hin   = (ushort*)alloc((size_t)NCH * DINNER * 16 * 2);
  ushort* ybf   = (ushort*)alloc((size_t)T_SEQ * DINNER * 2);

  auto kg1 = gemm_r8<1>;
  auto kg3 = gemm_r8<0>;
  hipFuncSetAttribute(reinterpret_cast<const void*>(kg1),
                      hipFuncAttributeMaxDynamicSharedMemorySize, 65536);
  hipFuncSetAttribute(reinterpret_cast<const void*>(kg3),
                      hipFuncAttributeMaxDynamicSharedMemorySize, 65536);

  // prep
  cast_bf16<<<(T_SEQ * DMODEL / 4 + 255) / 256, 256, 0, stream>>>(x, xbf, T_SEQ * DMODEL / 4);
  transpose_bf16<<<dim3(4096 / 32, 1024 / 32), dim3(32, 8), 0, stream>>>(W_in, winT, 1024, 4096);
  transpose_bf16<<<dim3(1024 / 32, 2048 / 32), dim3(32, 8), 0, stream>>>(W_out, woutT, 2048, 1024);
  wx_transpose_pad<<<(48 * 2048) / 256, 256, 0, stream>>>(W_x, wxT);

  // GEMM1: [xc|z] = x @ W_in (8192x4096, K=1024); 64m x 32n = 2048 blocks
  kg1<<<dim3(2048), 256, 65536, stream>>>(xbf, winT, xc, zb, 4096, 1024);

  // conv + silu
  conv_silu<<<(T_SEQ * DINNER) / 256, 256, 0, stream>>>(xc, conv_w, conv_b, xs);

  // GEMM2: xdbl = xs @ W_x (N=48 pad, split-K 4)
  gemm_thin<<<dim3(T_SEQ / 128, 4), 256, 0, stream>>>(xs, wxT, parts);
  reduce4<<<(T_SEQ * 48 / 4) / 256, 256, 0, stream>>>(parts, xdbl);

  // scan precompute
  precompute_k<<<T_SEQ / 256, 256, 0, stream>>>(xdbl, A_log, abar, bbar, ccb, dlt);
  chunkprod_k<<<(NCH * 16 + 255) / 256, 256, 0, stream>>>(dlt, A_log, P);

  // 3-pass chunked scan (bf16 carries)
  scan1<<<dim3(NCH, DINNER / 256), 256, 0, stream>>>(xs, abar, bbar, hend);
  scan2<<<(DINNER * 16) / 256, 256, 0, stream>>>(hend, P, hin);
  scan3<<<dim3(NCH, DINNER / 256), 256, 0, stream>>>(xs, zb, abar, bbar, ccb, hin, Dv, ybf);

  // GEMM3: out = y @ W_out (8192x1024, K=2048); 64m x 8n = 512 blocks
  kg3<<<dim3(512), 256, 65536, stream>>>(ybf, woutT, out, nullptr, 1024, 2048);
}

// Round 9
// 285.218 us; speedup vs baseline: 1.0961x; 1.0961x over previous
//
#include <hip/hip_runtime.h>
#include <hip/hip_bf16.h>

// ---------------- problem constants ----------------
#define T_SEQ 8192
#define DMODEL 1024
#define DINNER 2048          // DI
#define NSTATE 16            // DS
#define NCH 128              // scan chunks
#define CL 64                // chunk length (NCH*CL = T_SEQ)

typedef __attribute__((ext_vector_type(8))) short bf16x8;   // 8 bf16 = 4 VGPRs
typedef __attribute__((ext_vector_type(4))) float f32x4;    // MFMA C/D frag

__device__ __forceinline__ float bf2f(ushort u) {
  union { unsigned u; float f; } c; c.u = ((unsigned)u) << 16; return c.f;
}
__device__ __forceinline__ ushort f2bf(float f) {
  union { float f; unsigned u; } c; c.f = f;
  unsigned r = c.u + 0x7FFFu + ((c.u >> 16) & 1u);   // RNE
  return (ushort)(r >> 16);
}

#define GLD16(dst, src) __builtin_amdgcn_global_load_lds( \
    (const __attribute__((address_space(1))) void*)(src), \
    (__attribute__((address_space(3))) void*)(dst), 16, 0, 0)

template<int N> __device__ __forceinline__ void waitcnt_vm() {
  asm volatile("s_waitcnt vmcnt(%0)" :: "i"(N) : "memory");
}
#define LGKM0() do { asm volatile("s_waitcnt lgkmcnt(0)" ::: "memory"); \
                     __builtin_amdgcn_sched_barrier(0); } while (0)
// barrier + post-fence only (post-fence prevents next phase's ds_reads hoisting
// above the publish barrier = correctness; no pre-fence per m141)
#define BAR() do { __builtin_amdgcn_s_barrier(); \
                   __builtin_amdgcn_sched_barrier(0); } while (0)

// ---------------- fused prep kernel (cast + 2 transposes + wx pad) ----------------
// blocks [0,8192): cast x->bf16; [8192,12288): W_in^T; [12288,14336): W_out^T;
// [14336,14720): wx pad-transpose.
__global__ __launch_bounds__(256) void prep_all(const float* __restrict__ x,
                                                const float* __restrict__ W_in,
                                                const float* __restrict__ W_out,
                                                const float* __restrict__ Wx,
                                                ushort* __restrict__ xbf,
                                                ushort* __restrict__ winT,
                                                ushort* __restrict__ woutT,
                                                ushort* __restrict__ wxT) {
  __shared__ float tile[32][33];
  int b = blockIdx.x, tid = threadIdx.x;
  if (b < 8192) {                       // cast: 8192*256 float4
    int i = b * 256 + tid;
    float4 v = ((const float4*)x)[i];
    ushort4 o;
    o.x = f2bf(v.x); o.y = f2bf(v.y); o.z = f2bf(v.z); o.w = f2bf(v.w);
    ((ushort4*)xbf)[i] = o;
    return;
  }
  b -= 8192;
  const float* in; ushort* out; int R, C, bx, by;
  if (b < 4096)      { in = W_in;  out = winT;  R = 1024; C = 4096; bx = b & 127; by = b >> 7; }
  else if (b < 6144) { b -= 4096; in = W_out; out = woutT; R = 2048; C = 1024; bx = b & 31; by = b >> 5; }
  else {                                // wx pad: 384 blocks
    int idx = (b - 6144) * 256 + tid;   // 48*2048
    int j = idx >> 11, k = idx & 2047;
    wxT[idx] = (j < 33) ? f2bf(Wx[k * 33 + j]) : (ushort)0;
    return;
  }
  int xx = tid & 31, yy = tid >> 5;     // 32 x 8
  bx *= 32; by *= 32;
#pragma unroll
  for (int j = 0; j < 32; j += 8)
    tile[yy + j][xx] = in[(size_t)(by + yy + j) * C + bx + xx];
  __syncthreads();
#pragma unroll
  for (int j = 0; j < 32; j += 8)
    out[(size_t)(bx + yy + j) * R + by + xx] = f2bf(tile[xx][yy + j]);
}

// ------------- 8-phase GEMM (R7 structure, best measured): (MR*32)x256, BK=64 -------------
// 8 waves (2M x 4N), per-wave (MR*16)x64, acc[MR][4]. LDS 2-buf; swizzle: 16B slot
// s of 128B row r stored at s^(r&7), pre-swizzled global source (rule #21), same
// XOR on ds_read (measured 0 conflicts, R7). Phases per K-tile t (buf b=t&1):
//   P1: read a-lo+b01 | stage B1(t+1);  P2: read a-hi;
//   P3: read b23 | stage A0(t+2);       P4: stage A1,B0(t+2), counted vmcnt(VM).
// vmcnt(VM=2*AHL+2) forces t+1 landed (issued 4-6 phases back), keeps t+2 in
// flight. Downward read-sink past one barrier verified hazard-free (phase k's
// stages never touch regions phase k-1 reads). OUTMODE: 0=f32; 1=bf16 xc/z split.
template<int OUTMODE, int MR>
__global__ __launch_bounds__(512, 2)
void gemm8p(const ushort* __restrict__ A, const ushort* __restrict__ B,
            void* __restrict__ out0, void* __restrict__ out1,
            int N, int K, int MX) {
  constexpr int BM = MR * 32;
  constexpr int H = MR / 2;
  constexpr int AHL = BM / 128;
  constexpr int VM = 2 * AHL + 2;
  extern __shared__ __align__(16) char smem[];
  char* const sBr = smem + 2 * BM * 128;

  const int tid = threadIdx.x, lane = tid & 63, wid = tid >> 6;
  const int wm = wid >> 2, wn = wid & 3;
  const int xcd = blockIdx.x & 7, jb = blockIdx.x >> 3;
  const int mtile = xcd * MX + (jb % MX), ntile = jb / MX;
  const int mbase = mtile * BM, nbase = ntile * 256;
  const int NT = K >> 6;

  const int sr = tid >> 3;
  const int scol = ((tid & 7) ^ (sr & 7)) << 3;
  const ushort* pA = A + (size_t)(mbase + sr) * K + scol;
  const ushort* pB = B + (size_t)(nbase + sr) * K + scol;

  auto stgA = [&](int buf, int h, int tt) {
#pragma unroll
    for (int r = 0; r < AHL; ++r)
      GLD16(smem + buf * (BM * 128) + (h * (BM / 2) + r * 64) * 128 + wid * 1024,
            pA + (size_t)(h * (BM / 2) + r * 64) * K + (size_t)tt * 64);
  };
  auto stgB = [&](int buf, int h, int tt) {
#pragma unroll
    for (int r = 0; r < 2; ++r)
      GLD16(sBr + buf * 32768 + (h * 128 + r * 64) * 128 + wid * 1024,
            pB + (size_t)(h * 128 + r * 64) * K + (size_t)tt * 64);
  };

  const int frow = lane & 15, hh = lane >> 4;
  const int sw[2] = { ((hh) ^ (frow & 7)) << 4, ((4 + hh) ^ (frow & 7)) << 4 };
  const int arow = (wm * (MR * 16) + frow) * 128;
  const int brow = (wn * 64 + frow) * 128;

  f32x4 acc[MR][4];
#pragma unroll
  for (int m = 0; m < MR; ++m)
#pragma unroll
    for (int n = 0; n < 4; ++n) acc[m][n] = (f32x4){0.f, 0.f, 0.f, 0.f};

  stgA(0, 0, 0); stgA(0, 1, 0); stgB(0, 0, 0); stgB(0, 1, 0);
  if (NT > 1) { stgA(1, 0, 1); stgA(1, 1, 1); stgB(1, 0, 1); }
  waitcnt_vm<VM>();
  BAR();

  for (int t = 0; t < NT; ++t) {
    const int b = t & 1;
    const char* bA = smem + b * (BM * 128);
    const char* bB = sBr + b * 32768;
    bf16x8 alo[H][2], ahi[H][2], b01[2][2], b23[2][2];

    // ---- P1
#pragma unroll
    for (int m = 0; m < H; ++m)
#pragma unroll
      for (int kk = 0; kk < 2; ++kk)
        alo[m][kk] = *(const bf16x8*)(bA + arow + m * 2048 + sw[kk]);
#pragma unroll
    for (int n = 0; n < 2; ++n)
#pragma unroll
      for (int kk = 0; kk < 2; ++kk)
        b01[n][kk] = *(const bf16x8*)(bB + brow + n * 2048 + sw[kk]);
    if (t + 1 < NT) stgB((t + 1) & 1, 1, t + 1);
    BAR(); LGKM0();
    __builtin_amdgcn_s_setprio(1);
#pragma unroll
    for (int m = 0; m < H; ++m)
#pragma unroll
      for (int n = 0; n < 2; ++n)
#pragma unroll
        for (int kk = 0; kk < 2; ++kk)
          acc[m][n] = __builtin_amdgcn_mfma_f32_16x16x32_bf16(alo[m][kk], b01[n][kk], acc[m][n], 0, 0, 0);
    __builtin_amdgcn_s_setprio(0);
    BAR();

    // ---- P2
#pragma unroll
    for (int m = 0; m < H; ++m)
#pragma unroll
      for (int kk = 0; kk < 2; ++kk)
        ahi[m][kk] = *(const bf16x8*)(bA + arow + (H + m) * 2048 + sw[kk]);
    BAR(); LGKM0();
    __builtin_amdgcn_s_setprio(1);
#pragma unroll
    for (int m = 0; m < H; ++m)
#pragma unroll
      for (int n = 0; n < 2; ++n)
#pragma unroll
        for (int kk = 0; kk < 2; ++kk)
          acc[H + m][n] = __builtin_amdgcn_mfma_f32_16x16x32_bf16(ahi[m][kk], b01[n][kk], acc[H + m][n], 0, 0, 0);
    __builtin_amdgcn_s_setprio(0);
    BAR();

    // ---- P3
#pragma unroll
    for (int n = 0; n < 2; ++n)
#pragma unroll
      for (int kk = 0; kk < 2; ++kk)
        b23[n][kk] = *(const bf16x8*)(bB + brow + (2 + n) * 2048 + sw[kk]);
    if (t + 2 < NT) stgA(b, 0, t + 2);
    BAR(); LGKM0();
    __builtin_amdgcn_s_setprio(1);
#pragma unroll
    for (int m = 0; m < H; ++m)
#pragma unroll
      for (int n = 0; n < 2; ++n)
#pragma unroll
        for (int kk = 0; kk < 2; ++kk)
          acc[H + m][2 + n] = __builtin_amdgcn_mfma_f32_16x16x32_bf16(ahi[m][kk], b23[n][kk], acc[H + m][2 + n], 0, 0, 0);
    __builtin_amdgcn_s_setprio(0);
    BAR();

    // ---- P4
    if (t + 2 < NT) { stgA(b, 1, t + 2); stgB(b, 0, t + 2); }
    __builtin_amdgcn_s_setprio(1);
#pragma unroll
    for (int m = 0; m < H; ++m)
#pragma unroll
      for (int n = 0; n < 2; ++n)
#pragma unroll
        for (int kk = 0; kk < 2; ++kk)
          acc[m][2 + n] = __builtin_amdgcn_mfma_f32_16x16x32_bf16(alo[m][kk], b23[n][kk], acc[m][2 + n], 0, 0, 0);
    __builtin_amdgcn_s_setprio(0);
    if (t + 2 < NT) waitcnt_vm<VM>(); else waitcnt_vm<0>();
    BAR();
  }

  // epilogue: C/D layout col=lane&15, row=(lane>>4)*4+reg  [m89/m91]
  const int crow0 = mbase + wm * (MR * 16) + (lane >> 4) * 4;
  const int ccol0 = wn * 64 + (lane & 15);
  if (OUTMODE == 0) {
    float* po = (float*)out0;
#pragma unroll
    for (int m = 0; m < MR; ++m)
#pragma unroll
      for (int n = 0; n < 4; ++n)
#pragma unroll
        for (int j = 0; j < 4; ++j)
          po[(size_t)(crow0 + m * 16 + j) * N + nbase + ccol0 + n * 16] = acc[m][n][j];
  } else {
    ushort* dst = (nbase < 2048) ? (ushort*)out0 : (ushort*)out1;
    const int cbase = (nbase & 2047) + ccol0;
#pragma unroll
    for (int m = 0; m < MR; ++m)
#pragma unroll
      for (int n = 0; n < 4; ++n)
#pragma unroll
        for (int j = 0; j < 4; ++j)
          dst[(size_t)(crow0 + m * 16 + j) * 2048 + cbase + n * 16] = f2bf(acc[m][n][j]);
  }
}

// ---------------- thin GEMM: parts[j] = xs @ W_x (N=48 pad), 4-way split-K ----------------
__global__ __launch_bounds__(256) void gemm_thin(const ushort* __restrict__ A,
                                                 const ushort* __restrict__ Bw,
                                                 float* __restrict__ part) {
  __shared__ __align__(16) ushort sA[128 * 64];
  __shared__ __align__(16) ushort sB[48 * 64];
  const int tid = threadIdx.x, lane = tid & 63, wid = tid >> 6;
  const int mbase = blockIdx.x * 128;
  const int kbase = blockIdx.y * 512;
  const int frow = lane & 15, fke = (lane >> 4) * 8;

  f32x4 acc[2][3];
#pragma unroll
  for (int m = 0; m < 2; ++m)
#pragma unroll
    for (int n = 0; n < 3; ++n) acc[m][n] = (f32x4){0.f, 0.f, 0.f, 0.f};

  for (int k0 = 0; k0 < 512; k0 += 64) {
#pragma unroll
    for (int j = 0; j < 4; ++j) {
      int o = tid * 16 + j * 4096;
      int row = o >> 7, ke = ((o >> 4) & 7) * 8;
      GLD16((char*)sA + wid * 1024 + j * 4096,
            A + (size_t)(mbase + row) * DINNER + kbase + k0 + ke);
    }
    for (int i = tid; i < 384; i += 256) {
      int brow = i >> 3, kc = (i & 7) * 8;
      *(bf16x8*)&sB[brow * 64 + kc] = *(const bf16x8*)(Bw + (size_t)brow * DINNER + kbase + k0 + kc);
    }
    __syncthreads();
    bf16x8 af[2][2], bf_[3][2];
#pragma unroll
    for (int m = 0; m < 2; ++m)
#pragma unroll
      for (int ks = 0; ks < 2; ++ks)
        af[m][ks] = *(const bf16x8*)&sA[(wid * 32 + m * 16 + frow) * 64 + ks * 32 + fke];
#pragma unroll
    for (int n = 0; n < 3; ++n)
#pragma unroll
      for (int ks = 0; ks < 2; ++ks)
        bf_[n][ks] = *(const bf16x8*)&sB[(n * 16 + frow) * 64 + ks * 32 + fke];
#pragma unroll
    for (int m = 0; m < 2; ++m)
#pragma unroll
      for (int n = 0; n < 3; ++n)
#pragma unroll
        for (int ks = 0; ks < 2; ++ks)
          acc[m][n] = __builtin_amdgcn_mfma_f32_16x16x32_bf16(af[m][ks], bf_[n][ks], acc[m][n], 0, 0, 0);
    __syncthreads();
  }
  float* po = part + (size_t)blockIdx.y * (T_SEQ * 48);
#pragma unroll
  for (int m = 0; m < 2; ++m)
#pragma unroll
    for (int n = 0; n < 3; ++n)
#pragma unroll
      for (int j = 0; j < 4; ++j) {
        int rr = mbase + wid * 32 + m * 16 + (lane >> 4) * 4 + j;
        int cc = n * 16 + (lane & 15);
        po[(size_t)rr * 48 + cc] = acc[m][n][j];
      }
}

// -------- depthwise causal conv (DC=4) + silu, scalar (coalesced weights) --------
__global__ __launch_bounds__(256) void conv_silu(const ushort* __restrict__ xc,
                                                 const float* __restrict__ cw,
                                                 const float* __restrict__ cb,
                                                 ushort* __restrict__ xs) {
  int idx = blockIdx.x * 256 + threadIdx.x;
  int t = idx >> 11, d = idx & 2047;
  float4 w = *(const float4*)(cw + d * 4);
  float a = cb[d];
  const float wk[4] = {w.x, w.y, w.z, w.w};
#pragma unroll
  for (int k = 0; k < 4; ++k) {
    int tt = t - 3 + k;
    if (tt >= 0) a += bf2f(xc[(size_t)tt * 2048 + d]) * wk[k];
  }
  float s = a / (1.f + expf(-a));
  xs[idx] = f2bf(s);
}

// ---- fused: split-K reduce + delta/abar/bbar/cc + chunk products P ----
// grid 32 blocks x 256 threads; block handles t in [b*256, b*256+256) = 4 chunks.
__global__ __launch_bounds__(256) void precompute_k(const float* __restrict__ part,
                                                    const float* __restrict__ A_log,
                                                    float* __restrict__ abar,
                                                    float* __restrict__ bbar,
                                                    float* __restrict__ cc,
                                                    float* __restrict__ P) {
  __shared__ float ld[256 * 33];        // 33.8 KB
  const int t0 = blockIdx.x * 256, tid = threadIdx.x;
  for (int i = tid; i < 256 * 33; i += 256) {
    int r = i / 33, col = i - r * 33;
    size_t off = (size_t)(t0 + r) * 48 + col;
    ld[i] = part[off] + part[(size_t)T_SEQ * 48 + off] +
            part[2 * (size_t)T_SEQ * 48 + off] + part[3 * (size_t)T_SEQ * 48 + off];
  }
  __syncthreads();
  const float* r = &ld[tid * 33];
  float v = r[0];
  float delta = (v > 20.f) ? v : log1pf(expf(v));
  int t = t0 + tid;
#pragma unroll
  for (int n = 0; n < NSTATE; ++n) {
    float A = -expf(A_log[n]);
    abar[t * 16 + n] = expf(delta * A);
    bbar[t * 16 + n] = delta * r[1 + n];
    cc[t * 16 + n]   = r[17 + n];
  }
  // chunk sum of delta per wave (CL=64 = wave width)
  float s = delta;
#pragma unroll
  for (int off = 32; off > 0; off >>= 1) s += __shfl_down(s, off);
  s = __shfl(s, 0);
  int lane = tid & 63, c = blockIdx.x * 4 + (tid >> 6);
  if (lane < 16) P[c * 16 + lane] = expf(-expf(A_log[lane]) * s);
}

// ---------------- scan pass 1 (hend bf16) ----------------
__global__ __launch_bounds__(256) void scan1(const ushort* __restrict__ xs,
                                             const float* __restrict__ abar,
                                             const float* __restrict__ bbar,
                                             ushort* __restrict__ hend) {
  int c = blockIdx.x;
  int d = blockIdx.y * 256 + threadIdx.x;
  __shared__ float s_ab[CL * 16], s_bb[CL * 16];
  for (int e = threadIdx.x; e < CL * 16; e += 256) {
    s_ab[e] = abar[(size_t)c * CL * 16 + e];
    s_bb[e] = bbar[(size_t)c * CL * 16 + e];
  }
  __syncthreads();
  float h[16];
#pragma unroll
  for (int n = 0; n < 16; ++n) h[n] = 0.f;
  int tbase = c * CL;
  for (int i = 0; i < CL; ++i) {
    float x = bf2f(xs[(size_t)(tbase + i) * DINNER + d]);
#pragma unroll
    for (int n = 0; n < 16; ++n) h[n] = s_ab[i * 16 + n] * h[n] + s_bb[i * 16 + n] * x;
  }
  ushort* o = hend + ((size_t)c * DINNER + d) * 16;
  bf16x8 o0, o1;
#pragma unroll
  for (int q = 0; q < 8; ++q) { o0[q] = (short)f2bf(h[q]); o1[q] = (short)f2bf(h[8 + q]); }
  *(bf16x8*)o = o0;
  *(bf16x8*)(o + 8) = o1;
}

// ---------------- scan pass 2: blocked-prefetch carry scan (8 chunks/group) ----------------
__global__ __launch_bounds__(128) void scan2(const ushort* __restrict__ hend,
                                             const float* __restrict__ P,
                                             ushort* __restrict__ hin) {
  int idx = blockIdx.x * 128 + threadIdx.x;   // d*16 + n over 32768
  int n = idx & 15;
  float h = 0.f;
  for (int g = 0; g < 16; ++g) {
    float e[8], p[8];
#pragma unroll
    for (int j = 0; j < 8; ++j) {             // 16 independent loads issued together
      e[j] = bf2f(hend[(size_t)(g * 8 + j) * 32768 + idx]);
      p[j] = P[(g * 8 + j) * 16 + n];
    }
#pragma unroll
    for (int j = 0; j < 8; ++j) {
      hin[(size_t)(g * 8 + j) * 32768 + idx] = f2bf(h);
      h = p[j] * h + e[j];
    }
  }
}

// ---------------- scan pass 3 (hin bf16) ----------------
__global__ __launch_bounds__(256) void scan3(const ushort* __restrict__ xs,
                                             const ushort* __restrict__ zb,
                                             const float* __restrict__ abar,
                                             const float* __restrict__ bbar,
                                             const float* __restrict__ cc,
                                             const ushort* __restrict__ hin,
                                             const float* __restrict__ Dv,
                                             ushort* __restrict__ y) {
  int c = blockIdx.x;
  int d = blockIdx.y * 256 + threadIdx.x;
  __shared__ float s_ab[CL * 16], s_bb[CL * 16], s_cc[CL * 16];
  for (int e = threadIdx.x; e < CL * 16; e += 256) {
    s_ab[e] = abar[(size_t)c * CL * 16 + e];
    s_bb[e] = bbar[(size_t)c * CL * 16 + e];
    s_cc[e] = cc[(size_t)c * CL * 16 + e];
  }
  __syncthreads();
  float h[16];
  const ushort* hi = hin + ((size_t)c * DINNER + d) * 16;
  bf16x8 h0 = *(const bf16x8*)hi, h1 = *(const bf16x8*)(hi + 8);
#pragma unroll
  for (int q = 0; q < 8; ++q) { h[q] = bf2f((ushort)h0[q]); h[8 + q] = bf2f((ushort)h1[q]); }
  float Dd = Dv[d];
  int tbase = c * CL;
  for (int i = 0; i < CL; ++i) {
    size_t t = tbase + i;
    float x = bf2f(xs[t * DINNER + d]);
    float ys = 0.f;
#pragma unroll
    for (int n = 0; n < 16; ++n) {
      h[n] = s_ab[i * 16 + n] * h[n] + s_bb[i * 16 + n] * x;
      ys += s_cc[i * 16 + n] * h[n];
    }
    float z = bf2f(zb[t * 2048 + d]);
    float yv = (ys + Dd * x) * (z / (1.f + expf(-z)));
    y[t * DINNER + d] = f2bf(yv);
  }
}

// ---------------- launch ----------------
extern "C" void kernel_launch(void* const* d_in, const int* in_sizes, int n_in,
                              void* d_out, int out_size, void* d_ws, size_t ws_size,
                              hipStream_t stream) {
  const float* x      = (const float*)d_in[0];
  const float* W_in   = (const float*)d_in[1];
  const float* conv_w = (const float*)d_in[2];
  const float* conv_b = (const float*)d_in[3];
  const float* W_x    = (const float*)d_in[4];
  const float* A_log  = (const float*)d_in[5];
  const float* Dv     = (const float*)d_in[6];
  const float* W_out  = (const float*)d_in[7];
  float* out = (float*)d_out;

  char* w = (char*)d_ws;
  auto alloc = [&](size_t bytes) { char* p = w; w += (bytes + 255) & ~(size_t)255; return p; };

  ushort* xbf   = (ushort*)alloc((size_t)T_SEQ * DMODEL * 2);
  ushort* winT  = (ushort*)alloc((size_t)4096 * 1024 * 2);
  ushort* woutT = (ushort*)alloc((size_t)1024 * 2048 * 2);
  ushort* wxT   = (ushort*)alloc((size_t)48 * 2048 * 2);
  ushort* xc    = (ushort*)alloc((size_t)T_SEQ * DINNER * 2);
  ushort* zb    = (ushort*)alloc((size_t)T_SEQ * DINNER * 2);
  ushort* xs    = (ushort*)alloc((size_t)T_SEQ * DINNER * 2);
  float*  parts = (float*) alloc((size_t)4 * T_SEQ * 48 * 4);
  float*  abar  = (float*) alloc((size_t)T_SEQ * 16 * 4);
  float*  bbar  = (float*) alloc((size_t)T_SEQ * 16 * 4);
  float*  ccb   = (float*) alloc((size_t)T_SEQ * 16 * 4);
  float*  P     = (float*) alloc((size_t)NCH * 16 * 4);
  ushort* hend  = (ushort*)alloc((size_t)NCH * DINNER * 16 * 2);
  ushort* hin   = (ushort*)alloc((size_t)NCH * DINNER * 16 * 2);
  ushort* ybf   = (ushort*)alloc((size_t)T_SEQ * DINNER * 2);

  auto kg1 = gemm8p<1, 8>;   // 256x256
  auto kg3 = gemm8p<0, 4>;   // 128x256
  hipFuncSetAttribute(reinterpret_cast<const void*>(kg1),
                      hipFuncAttributeMaxDynamicSharedMemorySize, 131072);
  hipFuncSetAttribute(reinterpret_cast<const void*>(kg3),
                      hipFuncAttributeMaxDynamicSharedMemorySize, 98304);

  // fused prep: cast + W_in^T + W_out^T + wx pad
  prep_all<<<dim3(14720), 256, 0, stream>>>(x, W_in, W_out, W_x, xbf, winT, woutT, wxT);

  // GEMM1: [xc|z] = x @ W_in (8192x4096, K=1024); 512 blocks, MX=4
  kg1<<<dim3(512), 512, 131072, stream>>>(xbf, winT, xc, zb, 4096, 1024, 4);

  // conv + silu
  conv_silu<<<(T_SEQ * DINNER) / 256, 256, 0, stream>>>(xc, conv_w, conv_b, xs);

  // GEMM2: parts = xs @ W_x (N=48 pad, split-K 4)
  gemm_thin<<<dim3(T_SEQ / 128, 4), 256, 0, stream>>>(xs, wxT, parts);

  // fused reduce + precompute + chunk products
  precompute_k<<<32, 256, 0, stream>>>(parts, A_log, abar, bbar, ccb, P);

  // 3-pass chunked scan (bf16 carries)
  scan1<<<dim3(NCH, DINNER / 256), 256, 0, stream>>>(xs, abar, bbar, hend);
  scan2<<<256, 128, 0, stream>>>(hend, P, hin);
  scan3<<<dim3(NCH, DINNER / 256), 256, 0, stream>>>(xs, zb, abar, bbar, ccb, hin, Dv, ybf);

  // GEMM3: out = y @ W_out (8192x1024, K=2048); 256 blocks, MX=8
  kg3<<<dim3(256), 512, 98304, stream>>>(ybf, woutT, out, nullptr, 1024, 2048, 8);
}